// Round 1
// baseline (402.505 us; speedup 1.0000x reference)
//
#include <hip/hip_runtime.h>

#define M_SZ 32768
#define N_SZ 4096
#define DEPTHS 4
#define SPLITK 8
#define KCH 512  // N_SZ / SPLITK

typedef __attribute__((ext_vector_type(8))) short bh8;   // 8 bf16 (4 VGPR) MFMA frag
typedef __attribute__((ext_vector_type(4))) float f4;    // MFMA accumulator
typedef unsigned short u16;
typedef unsigned int u32;

__device__ __forceinline__ u16 f2bf(float f) {
  u32 u = __float_as_uint(f);
  u = (u + 0x7FFFu + ((u >> 16) & 1u)) >> 16;  // RNE
  return (u16)u;
}

__device__ __forceinline__ float fast_tanh(float x) {
  float ax = __builtin_fabsf(x);
  float e = __builtin_exp2f(ax * 2.8853900817779268f);  // e^(2|x|)
  float r = 1.0f - 2.0f * __builtin_amdgcn_rcpf(e + 1.0f);
  return __builtin_copysignf(r, x);
}

__device__ __forceinline__ void async16(const void* g, void* l) {
  __builtin_amdgcn_global_load_lds((const __attribute__((address_space(1))) u32*)g,
                                   (__attribute__((address_space(3))) u32*)l, 16, 0, 0);
}

// ---------------------------------------------------------------------------
// K1: y_d[i][n] = sum_k s[n][k] * Wd[i][k]   (write TRANSPOSED [i][n], bf16)
// grid (16, 16), block 256. W reads are wave-uniform -> scalar loads.
// ---------------------------------------------------------------------------
__global__ void k1_kernel(const float* __restrict__ s, const float* __restrict__ Wd,
                          u16* __restrict__ Ytd) {
  const int n = blockIdx.x * 256 + threadIdx.x;
  const int i0 = blockIdx.y * 8;
  float acc[8] = {0.f, 0.f, 0.f, 0.f, 0.f, 0.f, 0.f, 0.f};
  const float4* srow = (const float4*)(s + (size_t)n * 128);
#pragma unroll 4
  for (int k4 = 0; k4 < 32; ++k4) {
    float4 sv = srow[k4];
#pragma unroll
    for (int ii = 0; ii < 8; ++ii) {
      const float* w = Wd + (i0 + ii) * 128 + k4 * 4;
      acc[ii] = fmaf(sv.x, w[0], acc[ii]);
      acc[ii] = fmaf(sv.y, w[1], acc[ii]);
      acc[ii] = fmaf(sv.z, w[2], acc[ii]);
      acc[ii] = fmaf(sv.w, w[3], acc[ii]);
    }
  }
#pragma unroll
  for (int ii = 0; ii < 8; ++ii)
    Ytd[(size_t)(i0 + ii) * 4096 + n] = f2bf(acc[ii]);
}

// ---------------------------------------------------------------------------
// K2a: split-K partials of self_kernel @ y_d.
// tile 128(n) x 128(i), K-chunk 512, grid (32, SPLITK), 512 thr (8 waves 4x2).
// A: f32 -> bf16 reg-staged; B: bf16 via global_load_lds (pre-swizzled src).
// ---------------------------------------------------------------------------
__global__ __launch_bounds__(512, 4) void k2a_kernel(
    const float* __restrict__ SK, const u16* __restrict__ Ytd, float* __restrict__ Zp) {
  __shared__ char smem[32768];
  char* sA = smem;            // [128 rows][64 k] bf16, swizzled granules
  char* sB = smem + 16384;    // [128 cols][64 k] bf16, swizzled granules
  const int t = threadIdx.x, lane = t & 63, wid = t >> 6;
  const int wr = wid >> 1, wc = wid & 1;   // wave tile 32 rows x 64 cols
  const int n0 = blockIdx.x * 128;
  const int kbase = blockIdx.y * KCH;

  const int arow = t >> 2, akseg = t & 3;
  const float* agp = SK + (size_t)(n0 + arow) * 4096 + akseg * 16 + kbase;
  const int aw0 = arow * 128 + (((akseg * 2) ^ (arow & 7)) << 4);
  const int aw1 = arow * 128 + (((akseg * 2 + 1) ^ (arow & 7)) << 4);

  const int bcol = wid * 16 + (lane >> 3);
  const int bgs = (lane & 7) ^ (bcol & 7);
  const u16* bgp = Ytd + (size_t)bcol * 4096 + kbase + bgs * 8;
  char* sBw = sB + (wid * 16) * 128;

  const int l15 = lane & 15, l4 = lane >> 4, l7 = lane & 7;
  const int xg0 = (l4 ^ l7) << 4;
  const int xg1 = xg0 ^ 64;
  const int rbA = (wr * 32 + l15) * 128;
  const int cbB = (wc * 64 + l15) * 128;

  f4 acc[2][4];
#pragma unroll
  for (int i = 0; i < 2; ++i)
#pragma unroll
    for (int j = 0; j < 4; ++j) acc[i][j] = (f4){0.f, 0.f, 0.f, 0.f};

  for (int ks = 0; ks < KCH; ks += 64) {
    __syncthreads();
    async16(bgp + ks, sBw);
    async16(bgp + 8 * 4096 + ks, sBw + 1024);
    const float4* ag = (const float4*)(agp + ks);
    float4 v0 = ag[0], v1 = ag[1], v2 = ag[2], v3 = ag[3];
    union { bh8 v; u16 u[8]; } p0, p1;
    p0.u[0] = f2bf(v0.x); p0.u[1] = f2bf(v0.y); p0.u[2] = f2bf(v0.z); p0.u[3] = f2bf(v0.w);
    p0.u[4] = f2bf(v1.x); p0.u[5] = f2bf(v1.y); p0.u[6] = f2bf(v1.z); p0.u[7] = f2bf(v1.w);
    p1.u[0] = f2bf(v2.x); p1.u[1] = f2bf(v2.y); p1.u[2] = f2bf(v2.z); p1.u[3] = f2bf(v2.w);
    p1.u[4] = f2bf(v3.x); p1.u[5] = f2bf(v3.y); p1.u[6] = f2bf(v3.z); p1.u[7] = f2bf(v3.w);
    *(bh8*)(sA + aw0) = p0.v;
    *(bh8*)(sA + aw1) = p1.v;
    __syncthreads();
#pragma unroll
    for (int kk = 0; kk < 2; ++kk) {
      const int xg = kk ? xg1 : xg0;
      bh8 a0 = *(const bh8*)(sA + rbA + xg);
      bh8 a1 = *(const bh8*)(sA + rbA + 2048 + xg);
#pragma unroll
      for (int nf = 0; nf < 4; ++nf) {
        bh8 b = *(const bh8*)(sB + cbB + nf * 2048 + xg);
        acc[0][nf] = __builtin_amdgcn_mfma_f32_16x16x32_bf16(a0, b, acc[0][nf], 0, 0, 0);
        acc[1][nf] = __builtin_amdgcn_mfma_f32_16x16x32_bf16(a1, b, acc[1][nf], 0, 0, 0);
      }
    }
  }

  float* Z = Zp + (size_t)blockIdx.y * (N_SZ * 128) + (size_t)n0 * 128;
#pragma unroll
  for (int mf = 0; mf < 2; ++mf)
#pragma unroll
    for (int nf = 0; nf < 4; ++nf)
#pragma unroll
      for (int q = 0; q < 4; ++q) {
        int r = wr * 32 + mf * 16 + l4 * 4 + q;
        int c = wc * 64 + nf * 16 + l15;
        Z[r * 128 + c] = acc[mf][nf][q];
      }
}

// ---------------------------------------------------------------------------
// K2b: s[n][i] += tanh(sum_c Zp[c][n][i] + b[i])
// ---------------------------------------------------------------------------
__global__ void k2b_kernel(float* __restrict__ s, const float* __restrict__ Zp,
                           const float* __restrict__ bd) {
  int idx = blockIdx.x * 256 + threadIdx.x;
  float v = bd[idx & 127];
#pragma unroll
  for (int c = 0; c < SPLITK; ++c) v += Zp[(size_t)c * (N_SZ * 128) + idx];
  s[idx] += fast_tanh(v);
}

// ---------------------------------------------------------------------------
// phaseB: act_out = act + sum_d tanh(kernel @ y_d + b_d)
// One pass over the 512MB kernel matrix. Tile 128 rows x 512 cols (4 depths),
// 512 thr (8 waves 2x4); each wave holds all 4 depth blocks for its 64x32
// reduced-col slice -> the depth reduction is register-local.
// ---------------------------------------------------------------------------
__global__ __launch_bounds__(512, 2) void phaseB_kernel(
    const float* __restrict__ A, const u16* __restrict__ Yt,
    const float* __restrict__ act, const float* __restrict__ bias,
    float* __restrict__ outA) {
  __shared__ char smem[16384 + 65536];
  char* sA = smem;            // [128 rows][64 k] bf16 swizzled
  char* sB = smem + 16384;    // [512 cols][64 k] bf16 swizzled
  const int t = threadIdx.x, lane = t & 63, wid = t >> 6;
  const int wr = wid >> 2, wc = wid & 3;   // rows wr*64, reduced cols wc*32
  const int m0 = blockIdx.x * 128;

  const int arow = t >> 2, akseg = t & 3;
  const float* agp = A + (size_t)(m0 + arow) * 4096 + akseg * 16;
  const int aw0 = arow * 128 + (((akseg * 2) ^ (arow & 7)) << 4);
  const int aw1 = arow * 128 + (((akseg * 2 + 1) ^ (arow & 7)) << 4);

  const int bcol = wid * 64 + (lane >> 3);
  const int bgs = (lane & 7) ^ (bcol & 7);
  const u16* bgp = Yt + (size_t)bcol * 4096 + bgs * 8;
  char* sBw = sB + (wid * 64) * 128;

  const int l15 = lane & 15, l4 = lane >> 4, l7 = lane & 7;
  const int xg0 = (l4 ^ l7) << 4;
  const int xg1 = xg0 ^ 64;
  const int rbA = (wr * 64 + l15) * 128;
  const int cbB = wc * 4096 + l15 * 128;

  f4 acc[4][4][2];  // [mf][depth][n2]
#pragma unroll
  for (int i = 0; i < 4; ++i)
#pragma unroll
    for (int j = 0; j < 4; ++j)
#pragma unroll
      for (int k = 0; k < 2; ++k) acc[i][j][k] = (f4){0.f, 0.f, 0.f, 0.f};

  for (int k0 = 0; k0 < 4096; k0 += 64) {
    __syncthreads();
#pragma unroll
    for (int j = 0; j < 8; ++j)
      async16(bgp + (size_t)j * 32768 + k0, sBw + j * 1024);
    const float4* ag = (const float4*)(agp + k0);
    float4 v0 = ag[0], v1 = ag[1], v2 = ag[2], v3 = ag[3];
    union { bh8 v; u16 u[8]; } p0, p1;
    p0.u[0] = f2bf(v0.x); p0.u[1] = f2bf(v0.y); p0.u[2] = f2bf(v0.z); p0.u[3] = f2bf(v0.w);
    p0.u[4] = f2bf(v1.x); p0.u[5] = f2bf(v1.y); p0.u[6] = f2bf(v1.z); p0.u[7] = f2bf(v1.w);
    p1.u[0] = f2bf(v2.x); p1.u[1] = f2bf(v2.y); p1.u[2] = f2bf(v2.z); p1.u[3] = f2bf(v2.w);
    p1.u[4] = f2bf(v3.x); p1.u[5] = f2bf(v3.y); p1.u[6] = f2bf(v3.z); p1.u[7] = f2bf(v3.w);
    *(bh8*)(sA + aw0) = p0.v;
    *(bh8*)(sA + aw1) = p1.v;
    __syncthreads();
#pragma unroll
    for (int kk = 0; kk < 2; ++kk) {
      const int xg = kk ? xg1 : xg0;
      bh8 af[4];
#pragma unroll
      for (int mf = 0; mf < 4; ++mf) af[mf] = *(const bh8*)(sA + rbA + mf * 2048 + xg);
#pragma unroll
      for (int d = 0; d < 4; ++d)
#pragma unroll
        for (int n2 = 0; n2 < 2; ++n2) {
          bh8 b = *(const bh8*)(sB + cbB + d * 16384 + n2 * 2048 + xg);
#pragma unroll
          for (int mf = 0; mf < 4; ++mf)
            acc[mf][d][n2] =
                __builtin_amdgcn_mfma_f32_16x16x32_bf16(af[mf], b, acc[mf][d][n2], 0, 0, 0);
        }
    }
  }

  float bsv[4][2];
#pragma unroll
  for (int d = 0; d < 4; ++d) {
    bsv[d][0] = bias[d * 128 + wc * 32 + l15];
    bsv[d][1] = bias[d * 128 + wc * 32 + 16 + l15];
  }
#pragma unroll
  for (int mf = 0; mf < 4; ++mf)
#pragma unroll
    for (int q = 0; q < 4; ++q) {
      int r = m0 + wr * 64 + mf * 16 + l4 * 4 + q;
      int c = wc * 32 + l15;
      float s0 = 0.f, s1 = 0.f;
#pragma unroll
      for (int d = 0; d < 4; ++d) {
        s0 += fast_tanh(acc[mf][d][0][q] + bsv[d][0]);
        s1 += fast_tanh(acc[mf][d][1][q] + bsv[d][1]);
      }
      size_t o0 = (size_t)r * 128 + c;
      outA[o0] = act[o0] + s0;
      outA[o0 + 16] = act[o0 + 16] + s1;
    }
}

// ---------------------------------------------------------------------------
extern "C" void kernel_launch(void* const* d_in, const int* in_sizes, int n_in,
                              void* d_out, int out_size, void* d_ws, size_t ws_size,
                              hipStream_t stream) {
  const float* act = (const float*)d_in[0];
  const float* self_act = (const float*)d_in[1];
  const float* kern = (const float*)d_in[2];
  const float* self_kern = (const float*)d_in[3];
  const float* weights = (const float*)d_in[4];
  const float* bias = (const float*)d_in[5];
  float* out = (float*)d_out;
  float* s_buf = out + (size_t)M_SZ * 128;  // self_act state lives in its output slot

  u16* Yt = (u16*)d_ws;                                    // [512][4096] bf16, 4 MB
  float* Zp = (float*)((char*)d_ws + 4u * 1024 * 1024);    // [SPLITK][4096][128] f32, 16 MB

  hipMemcpyAsync(s_buf, self_act, (size_t)N_SZ * 128 * sizeof(float),
                 hipMemcpyDeviceToDevice, stream);

  for (int d = 0; d < DEPTHS; ++d) {
    k1_kernel<<<dim3(16, 16), 256, 0, stream>>>(s_buf, weights + d * 16384,
                                                Yt + (size_t)d * 128 * 4096);
    k2a_kernel<<<dim3(32, SPLITK), 512, 0, stream>>>(self_kern,
                                                     Yt + (size_t)d * 128 * 4096, Zp);
    k2b_kernel<<<2048, 256, 0, stream>>>(s_buf, Zp, bias + d * 128);
  }
  phaseB_kernel<<<256, 512, 0, stream>>>(kern, Yt, act, bias, out);
}

// Round 2
// 389.593 us; speedup vs baseline: 1.0331x; 1.0331x over previous
//
#include <hip/hip_runtime.h>

#define M_SZ 32768
#define N_SZ 4096
#define DEPTHS 4
#define SPLITK 8
#define KCH 512  // N_SZ / SPLITK

typedef __attribute__((ext_vector_type(8))) short bh8;   // 8 bf16 (4 VGPR) MFMA frag
typedef __attribute__((ext_vector_type(4))) float f4;    // MFMA accumulator
typedef unsigned short u16;
typedef unsigned int u32;

#define SBAR() __builtin_amdgcn_s_barrier()
#define FENCE() asm volatile("" ::: "memory")
#define WAITV(n) asm volatile("s_waitcnt vmcnt(" #n ")" ::: "memory")
#define WAITVL(n) asm volatile("s_waitcnt vmcnt(" #n ") lgkmcnt(0)" ::: "memory")

__device__ __forceinline__ u16 f2bf(float f) {
  u32 u = __float_as_uint(f);
  u = (u + 0x7FFFu + ((u >> 16) & 1u)) >> 16;  // RNE
  return (u16)u;
}

__device__ __forceinline__ float fast_tanh(float x) {
  float ax = __builtin_fabsf(x);
  float e = __builtin_exp2f(ax * 2.8853900817779268f);  // e^(2|x|)
  float r = 1.0f - 2.0f * __builtin_amdgcn_rcpf(e + 1.0f);
  return __builtin_copysignf(r, x);
}

__device__ __forceinline__ void async16(const void* g, void* l) {
  __builtin_amdgcn_global_load_lds((const __attribute__((address_space(1))) u32*)g,
                                   (__attribute__((address_space(3))) u32*)l, 16, 0, 0);
}

// ---------------------------------------------------------------------------
// K1: y_d[i][n] = sum_k s[n][k] * Wd[i][k]   (write TRANSPOSED [i][n], bf16)
// ---------------------------------------------------------------------------
__global__ void k1_kernel(const float* __restrict__ s, const float* __restrict__ Wd,
                          u16* __restrict__ Ytd) {
  const int n = blockIdx.x * 256 + threadIdx.x;
  const int i0 = blockIdx.y * 8;
  float acc[8] = {0.f, 0.f, 0.f, 0.f, 0.f, 0.f, 0.f, 0.f};
  const float4* srow = (const float4*)(s + (size_t)n * 128);
#pragma unroll 4
  for (int k4 = 0; k4 < 32; ++k4) {
    float4 sv = srow[k4];
#pragma unroll
    for (int ii = 0; ii < 8; ++ii) {
      const float* w = Wd + (i0 + ii) * 128 + k4 * 4;
      acc[ii] = fmaf(sv.x, w[0], acc[ii]);
      acc[ii] = fmaf(sv.y, w[1], acc[ii]);
      acc[ii] = fmaf(sv.z, w[2], acc[ii]);
      acc[ii] = fmaf(sv.w, w[3], acc[ii]);
    }
  }
#pragma unroll
  for (int ii = 0; ii < 8; ++ii)
    Ytd[(size_t)(i0 + ii) * 4096 + n] = f2bf(acc[ii]);
}

// ---------------------------------------------------------------------------
// K2a v2: split-K partials of self_kernel @ y_d, counted-vmcnt pipeline.
// tile 128(n) x 128(i), K-chunk 512, K-step 32 (16 iters), grid (32, SPLITK),
// 512 thr = 8 waves (2 row x 4 col), wave tile 64n x 32i.
// sA 8K single-buf (reg-prefetched A), sB 2x8K dbuf (async16 prefetched).
// ---------------------------------------------------------------------------
__global__ __launch_bounds__(512, 2) void k2a_kernel(
    const float* __restrict__ SK, const u16* __restrict__ Ytd, float* __restrict__ Zp) {
  __shared__ char smem[8192 + 2 * 8192];
  char* sA = smem;
  char* sB0 = smem + 8192;
  char* sB1 = smem + 8192 + 8192;
  const int t = threadIdx.x, lane = t & 63, wid = t >> 6;
  const int wr = wid >> 2, wc = wid & 3;
  const int n0 = blockIdx.x * 128;
  const int kbase = blockIdx.y * KCH;

  // A staging: 128 rows x 32 k f32; thread: row t>>2, k-octet t&3
  const int arow = t >> 2, kseg = t & 3;
  const float4* ag = (const float4*)(SK + (size_t)(n0 + arow) * 4096 + kbase + kseg * 8);
  const int awoff = arow * 64 + ((kseg ^ (arow & 3)) << 4);

  // B staging: 1 async16/thread (per wave 1KB = 16 cols of Yt)
  const int P = wid * 64 + lane;
  const int bcol = P >> 2;
  const int bg = (P & 3) ^ (bcol & 3);
  const u16* bsrc = Ytd + (size_t)bcol * 4096 + kbase + bg * 8;
  const int bldst = wid * 1024;  // wave-uniform

  const int l15 = lane & 15, l4 = lane >> 4;
  int aro[4], bro[2];
#pragma unroll
  for (int mf = 0; mf < 4; ++mf) {
    int row = wr * 64 + mf * 16 + l15;
    aro[mf] = row * 64 + ((l4 ^ (row & 3)) << 4);
  }
#pragma unroll
  for (int n2 = 0; n2 < 2; ++n2) {
    int col = wc * 32 + n2 * 16 + l15;
    bro[n2] = col * 64 + ((l4 ^ (col & 3)) << 4);
  }

  f4 acc[4][2];
#pragma unroll
  for (int i = 0; i < 4; ++i)
#pragma unroll
    for (int j = 0; j < 2; ++j) acc[i][j] = (f4){0.f, 0.f, 0.f, 0.f};

  // prologue: issue A(0) then B(0)
  float4 va0 = ag[0], va1 = ag[1];
  FENCE();
  async16(bsrc, sB0 + bldst);
  FENCE();

  char* sBc = sB0;
  char* sBn = sB1;
  for (int k = 0; k < 15; ++k) {
    SBAR(); FENCE();
    WAITV(1);  // A(k) regs ready (B(k) may fly)
    union { bh8 v; u16 u[8]; } p;
    p.u[0] = f2bf(va0.x); p.u[1] = f2bf(va0.y); p.u[2] = f2bf(va0.z); p.u[3] = f2bf(va0.w);
    p.u[4] = f2bf(va1.x); p.u[5] = f2bf(va1.y); p.u[6] = f2bf(va1.z); p.u[7] = f2bf(va1.w);
    *(bh8*)(sA + awoff) = p.v;
    FENCE();
    va0 = ag[(k + 1) * 8]; va1 = ag[(k + 1) * 8 + 1];  // issue A(k+1)
    FENCE();
    WAITVL(2);  // B(k) landed, my sA write done (A(k+1) stays in flight)
    SBAR(); FENCE();
    async16(bsrc + (k + 1) * 32, sBn + bldst);  // issue B(k+1)
    FENCE();
    bh8 af[4];
#pragma unroll
    for (int mf = 0; mf < 4; ++mf) af[mf] = *(const bh8*)(sA + aro[mf]);
#pragma unroll
    for (int n2 = 0; n2 < 2; ++n2) {
      bh8 b = *(const bh8*)(sBc + bro[n2]);
#pragma unroll
      for (int mf = 0; mf < 4; ++mf)
        acc[mf][n2] = __builtin_amdgcn_mfma_f32_16x16x32_bf16(af[mf], b, acc[mf][n2], 0, 0, 0);
    }
    char* tp = sBc; sBc = sBn; sBn = tp;
  }
  // peeled last iter (k = 15)
  SBAR(); FENCE();
  WAITV(1);
  {
    union { bh8 v; u16 u[8]; } p;
    p.u[0] = f2bf(va0.x); p.u[1] = f2bf(va0.y); p.u[2] = f2bf(va0.z); p.u[3] = f2bf(va0.w);
    p.u[4] = f2bf(va1.x); p.u[5] = f2bf(va1.y); p.u[6] = f2bf(va1.z); p.u[7] = f2bf(va1.w);
    *(bh8*)(sA + awoff) = p.v;
  }
  WAITVL(0);
  SBAR(); FENCE();
  {
    bh8 af[4];
#pragma unroll
    for (int mf = 0; mf < 4; ++mf) af[mf] = *(const bh8*)(sA + aro[mf]);
#pragma unroll
    for (int n2 = 0; n2 < 2; ++n2) {
      bh8 b = *(const bh8*)(sBc + bro[n2]);
#pragma unroll
      for (int mf = 0; mf < 4; ++mf)
        acc[mf][n2] = __builtin_amdgcn_mfma_f32_16x16x32_bf16(af[mf], b, acc[mf][n2], 0, 0, 0);
    }
  }

  float* Z = Zp + (size_t)blockIdx.y * (N_SZ * 128) + (size_t)n0 * 128;
#pragma unroll
  for (int mf = 0; mf < 4; ++mf)
#pragma unroll
    for (int n2 = 0; n2 < 2; ++n2)
#pragma unroll
      for (int q = 0; q < 4; ++q) {
        int r = wr * 64 + mf * 16 + l4 * 4 + q;
        int c = wc * 32 + n2 * 16 + l15;
        Z[r * 128 + c] = acc[mf][n2][q];
      }
}

// ---------------------------------------------------------------------------
// K2b: s[n][i] = prev[n][i] + tanh(sum_c Zp[c][n][i] + b[i])
// ---------------------------------------------------------------------------
__global__ void k2b_kernel(float* __restrict__ s, const float* __restrict__ Zp,
                           const float* __restrict__ bd) {
  int idx = blockIdx.x * 256 + threadIdx.x;
  float v = bd[idx & 127];
#pragma unroll
  for (int c = 0; c < SPLITK; ++c) v += Zp[(size_t)c * (N_SZ * 128) + idx];
  s[idx] += fast_tanh(v);
}

// ---------------------------------------------------------------------------
// phaseB v2: act_out = act + sum_d tanh(kernel @ y_d + b_d)
// One pass over the 512MB kernel matrix (HBM-bound: 64 FLOP/byte < 397).
// tile 128 rows x 512 cols (4 depths), K-step 32 (128 iters), 512 thr
// (8 waves 2x4), depth reduction register-local per wave.
// Counted-vmcnt pipeline: A reg-prefetch depth 1, B LDS-dbuf prefetch depth 1.
// LDS 72KB = sA 8K + sB 2x32K.
// ---------------------------------------------------------------------------
__global__ __launch_bounds__(512, 2) void phaseB_kernel(
    const float* __restrict__ A, const u16* __restrict__ Yt,
    const float* __restrict__ act, const float* __restrict__ bias,
    float* __restrict__ outA) {
  __shared__ char smem[8192 + 2 * 32768];
  char* sA = smem;
  char* sB0 = smem + 8192;
  char* sB1 = smem + 8192 + 32768;
  const int t = threadIdx.x, lane = t & 63, wid = t >> 6;
  const int wr = wid >> 2, wc = wid & 3;
  const int m0 = blockIdx.x * 128;

  const int arow = t >> 2, kseg = t & 3;
  const float4* ag = (const float4*)(A + (size_t)(m0 + arow) * 4096 + kseg * 8);
  const int awoff = arow * 64 + ((kseg ^ (arow & 3)) << 4);

  // B staging: 4 async16/thread (per wave 4 x 1KB), cols cb = d*128+i linear in Yt
  const u16* bsrc[4];
  int bldst[4];
#pragma unroll
  for (int j = 0; j < 4; ++j) {
    int P = wid * 256 + j * 64 + lane;
    int col = P >> 2;
    int g = (P & 3) ^ (col & 3);
    bsrc[j] = Yt + (size_t)col * 4096 + g * 8;
    bldst[j] = wid * 4096 + j * 1024;  // wave-uniform
  }

  const int l15 = lane & 15, l4 = lane >> 4;
  int aro[4], bro[4][2];
#pragma unroll
  for (int mf = 0; mf < 4; ++mf) {
    int row = wr * 64 + mf * 16 + l15;
    aro[mf] = row * 64 + ((l4 ^ (row & 3)) << 4);
  }
#pragma unroll
  for (int d = 0; d < 4; ++d)
#pragma unroll
    for (int n2 = 0; n2 < 2; ++n2) {
      int cb = d * 128 + wc * 32 + n2 * 16 + l15;
      bro[d][n2] = cb * 64 + ((l4 ^ (cb & 3)) << 4);
    }

  f4 acc[4][4][2];  // [mf][depth][n2]
#pragma unroll
  for (int i = 0; i < 4; ++i)
#pragma unroll
    for (int j = 0; j < 4; ++j)
#pragma unroll
      for (int k = 0; k < 2; ++k) acc[i][j][k] = (f4){0.f, 0.f, 0.f, 0.f};

  // prologue: issue A(0) then B(0)
  float4 va0 = ag[0], va1 = ag[1];
  FENCE();
#pragma unroll
  for (int j = 0; j < 4; ++j) async16(bsrc[j], sB0 + bldst[j]);
  FENCE();

  char* sBc = sB0;
  char* sBn = sB1;
  for (int k = 0; k < 127; ++k) {
    SBAR(); FENCE();
    WAITV(4);  // A(k) regs ready (4 B(k) may fly)
    union { bh8 v; u16 u[8]; } p;
    p.u[0] = f2bf(va0.x); p.u[1] = f2bf(va0.y); p.u[2] = f2bf(va0.z); p.u[3] = f2bf(va0.w);
    p.u[4] = f2bf(va1.x); p.u[5] = f2bf(va1.y); p.u[6] = f2bf(va1.z); p.u[7] = f2bf(va1.w);
    *(bh8*)(sA + awoff) = p.v;
    FENCE();
    va0 = ag[(k + 1) * 8]; va1 = ag[(k + 1) * 8 + 1];  // issue A(k+1)
    FENCE();
    WAITVL(2);  // B(k) landed + my sA write done (A(k+1) stays in flight)
    SBAR(); FENCE();
#pragma unroll
    for (int j = 0; j < 4; ++j) async16(bsrc[j] + (k + 1) * 32, sBn + bldst[j]);
    FENCE();
    bh8 af[4];
#pragma unroll
    for (int mf = 0; mf < 4; ++mf) af[mf] = *(const bh8*)(sA + aro[mf]);
#pragma unroll
    for (int d = 0; d < 4; ++d)
#pragma unroll
      for (int n2 = 0; n2 < 2; ++n2) {
        bh8 b = *(const bh8*)(sBc + bro[d][n2]);
#pragma unroll
        for (int mf = 0; mf < 4; ++mf)
          acc[mf][d][n2] =
              __builtin_amdgcn_mfma_f32_16x16x32_bf16(af[mf], b, acc[mf][d][n2], 0, 0, 0);
      }
    char* tp = sBc; sBc = sBn; sBn = tp;
  }
  // peeled last iter (k = 127)
  SBAR(); FENCE();
  WAITV(4);
  {
    union { bh8 v; u16 u[8]; } p;
    p.u[0] = f2bf(va0.x); p.u[1] = f2bf(va0.y); p.u[2] = f2bf(va0.z); p.u[3] = f2bf(va0.w);
    p.u[4] = f2bf(va1.x); p.u[5] = f2bf(va1.y); p.u[6] = f2bf(va1.z); p.u[7] = f2bf(va1.w);
    *(bh8*)(sA + awoff) = p.v;
  }
  WAITVL(0);
  SBAR(); FENCE();
  {
    bh8 af[4];
#pragma unroll
    for (int mf = 0; mf < 4; ++mf) af[mf] = *(const bh8*)(sA + aro[mf]);
#pragma unroll
    for (int d = 0; d < 4; ++d)
#pragma unroll
      for (int n2 = 0; n2 < 2; ++n2) {
        bh8 b = *(const bh8*)(sBc + bro[d][n2]);
#pragma unroll
        for (int mf = 0; mf < 4; ++mf)
          acc[mf][d][n2] =
              __builtin_amdgcn_mfma_f32_16x16x32_bf16(af[mf], b, acc[mf][d][n2], 0, 0, 0);
      }
  }

  float bsv[4][2];
#pragma unroll
  for (int d = 0; d < 4; ++d) {
    bsv[d][0] = bias[d * 128 + wc * 32 + l15];
    bsv[d][1] = bias[d * 128 + wc * 32 + 16 + l15];
  }
#pragma unroll
  for (int mf = 0; mf < 4; ++mf)
#pragma unroll
    for (int q = 0; q < 4; ++q) {
      int r = m0 + wr * 64 + mf * 16 + l4 * 4 + q;
      int c = wc * 32 + l15;
      float s0 = 0.f, s1 = 0.f;
#pragma unroll
      for (int d = 0; d < 4; ++d) {
        s0 += fast_tanh(acc[mf][d][0][q] + bsv[d][0]);
        s1 += fast_tanh(acc[mf][d][1][q] + bsv[d][1]);
      }
      size_t o0 = (size_t)r * 128 + c;
      outA[o0] = act[o0] + s0;
      outA[o0 + 16] = act[o0 + 16] + s1;
    }
}

// ---------------------------------------------------------------------------
extern "C" void kernel_launch(void* const* d_in, const int* in_sizes, int n_in,
                              void* d_out, int out_size, void* d_ws, size_t ws_size,
                              hipStream_t stream) {
  const float* act = (const float*)d_in[0];
  const float* self_act = (const float*)d_in[1];
  const float* kern = (const float*)d_in[2];
  const float* self_kern = (const float*)d_in[3];
  const float* weights = (const float*)d_in[4];
  const float* bias = (const float*)d_in[5];
  float* out = (float*)d_out;
  float* s_buf = out + (size_t)M_SZ * 128;  // self_act state lives in its output slot

  u16* Yt = (u16*)d_ws;                                    // [512][4096] bf16, 4 MB
  float* Zp = (float*)((char*)d_ws + 4u * 1024 * 1024);    // [SPLITK][4096][128] f32, 16 MB

  hipMemcpyAsync(s_buf, self_act, (size_t)N_SZ * 128 * sizeof(float),
                 hipMemcpyDeviceToDevice, stream);

  for (int d = 0; d < DEPTHS; ++d) {
    k1_kernel<<<dim3(16, 16), 256, 0, stream>>>(s_buf, weights + d * 16384,
                                                Yt + (size_t)d * 128 * 4096);
    k2a_kernel<<<dim3(32, SPLITK), 512, 0, stream>>>(self_kern,
                                                     Yt + (size_t)d * 128 * 4096, Zp);
    k2b_kernel<<<2048, 256, 0, stream>>>(s_buf, Zp, bias + d * 128);
  }
  phaseB_kernel<<<256, 512, 0, stream>>>(kern, Yt, act, bias, out);
}